// Round 10
// baseline (1721.161 us; speedup 1.0000x reference)
//
#include <hip/hip_runtime.h>
#include <math.h>

constexpr int B = 8;
constexpr int N = 50000;
constexpr int E = 400000;
constexpr int NH = 25000;
constexpr float BN_EPS = 1e-5f;
constexpr float NEG = 0.01f;

// ------------------------- bf16 helpers -------------------------

__device__ __forceinline__ unsigned clamp_src(int s) {
    unsigned u = (unsigned)s;
    return (u < (unsigned)N) ? u : 0u;
}

__device__ __forceinline__ unsigned pack_bf16(float a, float b) {
    unsigned ua = __float_as_uint(a);
    unsigned ub = __float_as_uint(b);
    ua = (ua + 0x7FFFu + ((ua >> 16) & 1u)) >> 16;
    ub = (ub + 0x7FFFu + ((ub >> 16) & 1u)) >> 16;
    return (ub << 16) | (ua & 0xFFFFu);
}
__device__ __forceinline__ float unpack_lo(unsigned u) { return __uint_as_float(u << 16); }
__device__ __forceinline__ float unpack_hi(unsigned u) { return __uint_as_float(u & 0xFFFF0000u); }

// ------------------------- CSR construction (source-bucketed) -------------------------

__global__ __launch_bounds__(256) void deg2_kernel(const int* __restrict__ row, const int* __restrict__ col,
                                                   float* __restrict__ deg, int* __restrict__ deg_lo) {
    int e = blockIdx.x * blockDim.x + threadIdx.x;
    if (e >= E) return;
    unsigned r = clamp_src(row[e]), c = clamp_src(col[e]);
    atomicAdd(&deg[c], 1.0f);
    if (r < (unsigned)NH) atomicAdd(&deg_lo[c], 1);
}

__global__ __launch_bounds__(256) void scan1_kernel(const float* __restrict__ deg,
                                                    int* __restrict__ part, int* __restrict__ bsum) {
    __shared__ int sm[4];
    int i = blockIdx.x * blockDim.x + threadIdx.x;
    int v = (i < N) ? (int)deg[i] : 0;
    int lane = threadIdx.x & 63, wv = threadIdx.x >> 6;
    int x = v;
#pragma unroll
    for (int off = 1; off < 64; off <<= 1) {
        int t = __shfl_up(x, off);
        if (lane >= off) x += t;
    }
    if (lane == 63) sm[wv] = x;
    __syncthreads();
    int add = 0;
#pragma unroll
    for (int w = 0; w < 4; ++w) if (w < wv) add += sm[w];
    if (i < N) part[i] = x - v + add;
    if (threadIdx.x == blockDim.x - 1) bsum[blockIdx.x] = x + add;
}

__global__ __launch_bounds__(256) void scan2_kernel(const int* __restrict__ bsum, int* __restrict__ boff,
                                                    int nb, int* __restrict__ rowptr) {
    __shared__ int sm[4];
    int i = threadIdx.x;
    int v = (i < nb) ? bsum[i] : 0;
    int lane = i & 63, wv = i >> 6;
    int x = v;
#pragma unroll
    for (int off = 1; off < 64; off <<= 1) {
        int t = __shfl_up(x, off);
        if (lane >= off) x += t;
    }
    if (lane == 63) sm[wv] = x;
    __syncthreads();
    int add = 0;
#pragma unroll
    for (int w = 0; w < 4; ++w) if (w < wv) add += sm[w];
    if (i < nb) boff[i] = x - v + add;
    if (i == 0) rowptr[N] = E;
}

__global__ __launch_bounds__(256) void scan3_kernel(const int* __restrict__ part, const int* __restrict__ boff,
                                                    int* __restrict__ rowptr) {
    int i = blockIdx.x * blockDim.x + threadIdx.x;
    if (i < N) rowptr[i] = part[i] + boff[blockIdx.x];
}

__global__ __launch_bounds__(256) void fill_kernel(const int* __restrict__ row, const int* __restrict__ col,
                                                   const int* __restrict__ rowptr, const int* __restrict__ deg_lo,
                                                   int* __restrict__ cur_lo, int* __restrict__ cur_hi,
                                                   int* __restrict__ csr_src) {
    int e = blockIdx.x * blockDim.x + threadIdx.x;
    if (e >= E) return;
    unsigned r = clamp_src(row[e]), c = clamp_src(col[e]);
    unsigned p;
    if (r < (unsigned)NH)
        p = (unsigned)(rowptr[c] + atomicAdd(&cur_lo[c], 1));
    else
        p = (unsigned)(rowptr[c] + deg_lo[c] + atomicAdd(&cur_hi[c], 1));
    if (p >= (unsigned)E) p = E - 1;
    csr_src[p] = (int)r;
}

__global__ __launch_bounds__(256) void dis_kernel(float* __restrict__ deg) {
    int i = blockIdx.x * blockDim.x + threadIdx.x;
    if (i < N) {
        float d = deg[i];
        deg[i] = (d > 0.f) ? rsqrtf(d) : 0.f;
    }
}

// ------------------------- 4-dim propagation (layer 0), batch-pinned, bf16 out ---------

template<bool INBF>
__global__ __launch_bounds__(256) void xprop_kernel(const void* __restrict__ xin, const int* __restrict__ rowptr,
                                                    const int* __restrict__ csr_src, const float* __restrict__ dis,
                                                    uint2* __restrict__ xout) {
    int b = blockIdx.x & 7;
    int n = (blockIdx.x >> 3) * blockDim.x + threadIdx.x;
    if (n >= N) return;
    float a0 = 0.f, a1 = 0.f, a2 = 0.f, a3 = 0.f;
    int beg = rowptr[n], end = rowptr[n + 1];
    if (beg < 0) beg = 0;
    if (end > E) end = E;
    for (int i = beg; i < end; ++i) {
        unsigned s = clamp_src(csr_src[i]);
        float w = dis[s];
        if constexpr (!INBF) {
            float4 v = *((const float4*)xin + (size_t)b * N + s);
            a0 = fmaf(w, v.x, a0); a1 = fmaf(w, v.y, a1);
            a2 = fmaf(w, v.z, a2); a3 = fmaf(w, v.w, a3);
        } else {
            uint2 v = *((const uint2*)xin + (size_t)b * N + s);
            a0 = fmaf(w, unpack_lo(v.x), a0); a1 = fmaf(w, unpack_hi(v.x), a1);
            a2 = fmaf(w, unpack_lo(v.y), a2); a3 = fmaf(w, unpack_hi(v.y), a3);
        }
    }
    float dn = dis[n];
    uint2 o;
    o.x = pack_bf16(a0 * dn, a1 * dn);
    o.y = pack_bf16(a2 * dn, a3 * dn);
    xout[(size_t)b * N + n] = o;
}

// ------------------------- 16-dim concat row loader -------------------------

__device__ __forceinline__ void load_xv(const float4* __restrict__ x0, const uint2* __restrict__ x1,
                                        const uint2* __restrict__ x2, const uint2* __restrict__ x3,
                                        size_t ro, float xv[16]) {
    float4 v = x0[ro];
    xv[0] = v.x; xv[1] = v.y; xv[2] = v.z; xv[3] = v.w;
    uint2 u1 = x1[ro], u2 = x2[ro], u3 = x3[ro];
    xv[4] = unpack_lo(u1.x); xv[5] = unpack_hi(u1.x); xv[6] = unpack_lo(u1.y); xv[7] = unpack_hi(u1.y);
    xv[8] = unpack_lo(u2.x); xv[9] = unpack_hi(u2.x); xv[10] = unpack_lo(u2.y); xv[11] = unpack_hi(u2.y);
    xv[12] = unpack_lo(u3.x); xv[13] = unpack_hi(u3.x); xv[14] = unpack_lo(u3.y); xv[15] = unpack_hi(u3.y);
}

// ------------------------- build h1 = leaky(BN0([x|x1|x2|x3] @ W0)), bf16 full batch ----

__global__ __launch_bounds__(256) void build_h1_kernel(const float4* __restrict__ x0, const uint2* __restrict__ x1,
                                                       const uint2* __restrict__ x2, const uint2* __restrict__ x3,
                                                       const float* __restrict__ W0,
                                                       const float* __restrict__ gamma, const float* __restrict__ beta,
                                                       uint4* __restrict__ h1) {
    int gid = blockIdx.x * blockDim.x + threadIdx.x;
    int node = gid >> 6;
    int lane = gid & 63;
    int fg = lane >> 3, b = lane & 7;
    if (node >= N) return;
    size_t ro = (size_t)b * N + node;
    float xv[16];
    load_xv(x0, x1, x2, x3, ro, xv);
    float z[8];
#pragma unroll
    for (int j = 0; j < 8; ++j) z[j] = 0.f;
#pragma unroll
    for (int kf = 0; kf < 16; ++kf) {
        const float* wr = W0 + kf * 64 + fg * 8;
        float4 wa = *(const float4*)wr;
        float4 wb = *(const float4*)(wr + 4);
        float xs = xv[kf];
        z[0] = fmaf(xs, wa.x, z[0]); z[1] = fmaf(xs, wa.y, z[1]);
        z[2] = fmaf(xs, wa.z, z[2]); z[3] = fmaf(xs, wa.w, z[3]);
        z[4] = fmaf(xs, wb.x, z[4]); z[5] = fmaf(xs, wb.y, z[5]);
        z[6] = fmaf(xs, wb.z, z[6]); z[7] = fmaf(xs, wb.w, z[7]);
    }
    const float* gp = gamma + (size_t)node * 64 + fg * 8;
    const float* bp = beta + (size_t)node * 64 + fg * 8;
    float h[8];
#pragma unroll
    for (int j = 0; j < 8; ++j) {
        float v = z[j];
        float s = v, s2 = v * v;
        s += __shfl_xor(s, 1);  s += __shfl_xor(s, 2);  s += __shfl_xor(s, 4);
        s2 += __shfl_xor(s2, 1); s2 += __shfl_xor(s2, 2); s2 += __shfl_xor(s2, 4);
        float mean = s * 0.125f;
        float var = fmaf(-mean, mean, s2 * 0.125f);
        float rs = rsqrtf(var + BN_EPS);
        float o = fmaf(gp[j] * rs, v - mean, bp[j]);
        h[j] = (o >= 0.f) ? o : NEG * o;
    }
    uint4 o;
    o.x = pack_bf16(h[0], h[1]);
    o.y = pack_bf16(h[2], h[3]);
    o.z = pack_bf16(h[4], h[5]);
    o.w = pack_bf16(h[6], h[7]);
    h1[ro * 8 + fg] = o;
}

// ------------------------- wave-cooperative Horner hop -------------------------
// Wave owns 64 nodes. Phase A: 32-lane/node coalesced gather -> LDS (transposed, pad-65).
// Phase B: thread-per-node; gather row from LDS, x dis_n, + bias. Phase C: stage h1 rows
// cooperatively -> LDS. Phase D: dense 64x64, h from LDS, W wave-uniform (SGPR).
// Phase E: pack acc -> LDS, cooperative coalesced 128B stores.
// All LDS traffic is wave-private (no __syncthreads). u layout: uint[bl][N][32].

template<int MODE>
__global__ __launch_bounds__(256, 4) void hopW_kernel(const unsigned* __restrict__ u_in, const int* __restrict__ rowptr,
                                                      const int* __restrict__ csr_src, const float* __restrict__ dis,
                                                      const unsigned* __restrict__ h1, int b0, int bmask, int bshift,
                                                      const float* __restrict__ Wk, const float* __restrict__ bias,
                                                      unsigned* __restrict__ u_out) {
    __shared__ unsigned lds[4][32][65];
    int bl = blockIdx.x & bmask;
    int w = threadIdx.x >> 6;
    int lane = threadIdx.x & 63;
    int half = lane >> 5, l = lane & 31;
    int wbase = (blockIdx.x >> bshift) * 256 + w * 64;
    unsigned (*L)[65] = lds[w];

    // Phase A: cooperative gather, 2 nodes per sweep
    if constexpr (MODE > 0) {
        const unsigned* ub = u_in + (size_t)bl * N * 32;
        for (int j = 0; j < 32; ++j) {
            int n = wbase + 2 * j + half;
            float a0 = 0.f, a1 = 0.f;
            if (n < N) {
                int beg = rowptr[n], end = rowptr[n + 1];
                if (beg < 0) beg = 0;
                if (end > E) end = E;
                for (int i = beg; i < end; ++i) {
                    unsigned s = clamp_src(csr_src[i]);
                    float wgt = dis[s];
                    unsigned v = ub[(size_t)s * 32 + l];
                    a0 = fmaf(wgt, unpack_lo(v), a0);
                    a1 = fmaf(wgt, unpack_hi(v), a1);
                }
            }
            L[l][2 * j + half] = pack_bf16(a0, a1);
        }
    }

    // Phase B: thread-per-node accumulator init
    int node = wbase + lane;
    int nodec = (node < N) ? node : N - 1;
    float acc[64];
    if constexpr (MODE > 0) {
        float dn = dis[nodec];
#pragma unroll
        for (int q = 0; q < 32; ++q) {
            unsigned u = L[q][lane];
            acc[2 * q]     = unpack_lo(u) * dn;
            acc[2 * q + 1] = unpack_hi(u) * dn;
        }
    } else {
#pragma unroll
        for (int f = 0; f < 64; ++f) acc[f] = 0.f;
    }
    if constexpr (MODE == 2) {
#pragma unroll
        for (int f = 0; f < 64; ++f) acc[f] += bias[f];
    }

    // Phase C: stage h1 rows cooperatively (overwrites consumed gather data)
    {
        const unsigned* hb = h1 + (size_t)(b0 + bl) * N * 32;
        for (int j = 0; j < 32; ++j) {
            int n = wbase + 2 * j + half;
            unsigned hv = (n < N) ? hb[(size_t)n * 32 + l] : 0u;
            L[l][2 * j + half] = hv;
        }
    }

    // Phase D: dense 64x64, W wave-uniform -> SGPR broadcast
#pragma unroll 1
    for (int k2 = 0; k2 < 32; ++k2) {
        unsigned hu = L[k2][lane];
        float h0 = unpack_lo(hu), h1f = unpack_hi(hu);
        const float* w0 = Wk + 2 * k2 * 64;
#pragma unroll
        for (int c = 0; c < 64; ++c)
            acc[c] = fmaf(h0, w0[c], acc[c]);
#pragma unroll
        for (int c = 0; c < 64; ++c)
            acc[c] = fmaf(h1f, w0[64 + c], acc[c]);
    }

    // Phase E: pack -> LDS, cooperative coalesced stores
#pragma unroll
    for (int q = 0; q < 32; ++q)
        L[q][lane] = pack_bf16(acc[2 * q], acc[2 * q + 1]);
    unsigned* ob = u_out + (size_t)bl * N * 32;
    for (int j = 0; j < 32; ++j) {
        int n = wbase + 2 * j + half;
        if (n < N) ob[(size_t)n * 32 + l] = L[l][2 * j + half];
    }
}

// ------------------------- BN1 + leaky + W2 projection -------------------------

__global__ __launch_bounds__(256) void bn_project_kernel(const uint4* __restrict__ zlo, const uint4* __restrict__ zhi,
                                                         const float* __restrict__ gamma, const float* __restrict__ beta,
                                                         const float* __restrict__ W2, float* __restrict__ y) {
    int gid = blockIdx.x * blockDim.x + threadIdx.x;
    int node = gid >> 6;
    int lane = gid & 63;
    int fg = lane >> 3, b = lane & 7;
    if (node >= N) return;
    const uint4* zp = (b < 4) ? (zlo + ((size_t)b * N + node) * 8)
                              : (zhi + ((size_t)(b - 4) * N + node) * 8);
    uint4 v = zp[fg];
    float h[8] = {unpack_lo(v.x), unpack_hi(v.x), unpack_lo(v.y), unpack_hi(v.y),
                  unpack_lo(v.z), unpack_hi(v.z), unpack_lo(v.w), unpack_hi(v.w)};
    const float* gp = gamma + (size_t)node * 64 + fg * 8;
    const float* bp = beta + (size_t)node * 64 + fg * 8;
#pragma unroll
    for (int j = 0; j < 8; ++j) {
        float val = h[j];
        float s = val, s2 = val * val;
        s += __shfl_xor(s, 1);  s += __shfl_xor(s, 2);  s += __shfl_xor(s, 4);
        s2 += __shfl_xor(s2, 1); s2 += __shfl_xor(s2, 2); s2 += __shfl_xor(s2, 4);
        float mean = s * 0.125f;
        float var = fmaf(-mean, mean, s2 * 0.125f);
        float rs = rsqrtf(var + BN_EPS);
        float o = fmaf(gp[j] * rs, val - mean, bp[j]);
        h[j] = (o >= 0.f) ? o : NEG * o;
    }
    float p[12];
#pragma unroll
    for (int k = 0; k < 4; ++k) {
#pragma unroll
        for (int c = 0; c < 3; ++c) {
            float s = 0.f;
#pragma unroll
            for (int j = 0; j < 8; ++j)
                s = fmaf(h[j], W2[k * 192 + (fg * 8 + j) * 3 + c], s);
            p[k * 3 + c] = s;
        }
    }
#pragma unroll
    for (int t = 8; t < 64; t <<= 1) {
#pragma unroll
        for (int i = 0; i < 12; ++i)
            p[i] += __shfl_xor(p[i], t);
    }
    if (fg == 0) {
        size_t bn3 = ((size_t)b * N + node) * 3;
#pragma unroll
        for (int k = 0; k < 4; ++k)
#pragma unroll
            for (int c = 0; c < 3; ++c)
                y[(size_t)k * B * N * 3 + bn3 + c] = p[k * 3 + c];
    }
}

// ------------------------- 3-dim propagation (layer 2 Horner) -------------------------

__global__ __launch_bounds__(256) void qprop_kernel(const float* __restrict__ vin, const int* __restrict__ rowptr,
                                                    const int* __restrict__ csr_src, const float* __restrict__ dis,
                                                    const float* __restrict__ add, float* __restrict__ vout) {
    int b = blockIdx.x & 7;
    int n = (blockIdx.x >> 3) * blockDim.x + threadIdx.x;
    if (n >= N) return;
    float a0 = 0.f, a1 = 0.f, a2 = 0.f;
    int beg = rowptr[n], end = rowptr[n + 1];
    if (beg < 0) beg = 0;
    if (end > E) end = E;
    const float* base = vin + (size_t)b * N * 3;
    for (int i = beg; i < end; ++i) {
        unsigned s = clamp_src(csr_src[i]);
        float w = dis[s];
        const float* p = base + (size_t)s * 3;
        a0 = fmaf(w, p[0], a0);
        a1 = fmaf(w, p[1], a1);
        a2 = fmaf(w, p[2], a2);
    }
    float dn = dis[n];
    const float* ap = add + ((size_t)b * N + n) * 3;
    float* op = vout + ((size_t)b * N + n) * 3;
    op[0] = fmaf(a0, dn, ap[0]);
    op[1] = fmaf(a1, dn, ap[1]);
    op[2] = fmaf(a2, dn, ap[2]);
}

__global__ __launch_bounds__(256) void qfinal_kernel(const float* __restrict__ vin, const int* __restrict__ rowptr,
                                                     const int* __restrict__ csr_src, const float* __restrict__ dis,
                                                     const float* __restrict__ y0, const float* __restrict__ b2,
                                                     const float* __restrict__ vmin, const float* __restrict__ vmax,
                                                     float* __restrict__ out) {
    int b = blockIdx.x & 7;
    int n = (blockIdx.x >> 3) * blockDim.x + threadIdx.x;
    if (n >= N) return;
    float a0 = 0.f, a1 = 0.f, a2 = 0.f;
    int beg = rowptr[n], end = rowptr[n + 1];
    if (beg < 0) beg = 0;
    if (end > E) end = E;
    const float* base = vin + (size_t)b * N * 3;
    for (int i = beg; i < end; ++i) {
        unsigned s = clamp_src(csr_src[i]);
        float w = dis[s];
        const float* p = base + (size_t)s * 3;
        a0 = fmaf(w, p[0], a0);
        a1 = fmaf(w, p[1], a1);
        a2 = fmaf(w, p[2], a2);
    }
    float dn = dis[n];
    size_t bn3 = ((size_t)b * N + n) * 3;
    const float* yp = y0 + bn3;
    float g0 = fmaf(a0, dn, yp[0]) + b2[0];
    float g1 = fmaf(a1, dn, yp[1]) + b2[1];
    float g2 = fmaf(a2, dn, yp[2]) + b2[2];
    float mn0 = vmin[n * 3 + 0], mx0 = vmax[n * 3 + 0];
    float mn1 = vmin[n * 3 + 1], mx1 = vmax[n * 3 + 1];
    float mn2 = vmin[n * 3 + 2], mx2 = vmax[n * 3 + 2];
    float* op = out + bn3;
    op[0] = mn0 + (mx0 - mn0) / (1.f + expf(g0));
    op[1] = mn1 + (mx1 - mn1) / (1.f + expf(g1));
    op[2] = mn2 + (mx2 - mn2) / (1.f + expf(g2));
}

// ------------------------- host launcher -------------------------

extern "C" void kernel_launch(void* const* d_in, const int* in_sizes, int n_in,
                              void* d_out, int out_size, void* d_ws, size_t ws_size,
                              hipStream_t stream) {
    const float* x      = (const float*)d_in[0];
    const int*   ei     = (const int*)d_in[1];
    const int*   rowi   = ei;
    const int*   coli   = ei + E;
    const float* vmin   = (const float*)d_in[2];
    const float* vmax   = (const float*)d_in[3];
    const float* W0     = (const float*)d_in[4];
    const float* W1     = (const float*)d_in[6];
    const float* b1v    = (const float*)d_in[7];
    const float* W2     = (const float*)d_in[8];
    const float* b2v    = (const float*)d_in[9];
    const float* gamma0 = (const float*)d_in[10];
    const float* beta0  = (const float*)d_in[11];
    const float* gamma1 = (const float*)d_in[12];
    const float* beta1  = (const float*)d_in[13];
    float* out = (float*)d_out;

    const size_t BN3  = (size_t)B * N * 3;
    const size_t H1FL = (size_t)B * N * 32;        // 12.8M fl = 51.2 MB
    const size_t UCFL = (size_t)4 * N * 32;        // 6.4M fl  = 25.6 MB
    const size_t XBFL = (size_t)B * N * 2;

    auto rnd = [](size_t nf) { return (nf + 63) & ~(size_t)63; };
    size_t off = 0;
    auto alloc = [&](size_t nfloats) -> float* {
        float* p = (float*)d_ws + off;
        off += rnd(nfloats);
        return p;
    };
    float* deg     = alloc(N);                     // becomes dis
    int*   deg_lo  = (int*)alloc(N);
    int*   rowptr  = (int*)alloc(N + 1);
    int*   part    = (int*)alloc(N);
    int*   bsum    = (int*)alloc(256);
    int*   boff    = (int*)alloc(256);
    int*   cur_lo  = (int*)alloc(N);
    int*   cur_hi  = (int*)alloc(N);
    int*   csr_src = (int*)alloc(E);
    float* h1      = alloc(H1FL);

    const size_t avail_fl = ws_size / 4;
    const size_t need_full = off + 2 * H1FL + 4096;
    bool full = (avail_fl >= need_full);

    float *uA, *uB, *uC = nullptr;
    if (full) {
        uA = alloc(H1FL);
        uB = alloc(H1FL);
    } else {
        uA = alloc(UCFL);
        uB = alloc(UCFL);
        uC = alloc(UCFL);
    }
    uint2* xb1 = (uint2*)uA;
    uint2* xb2 = (uint2*)((float*)uA + XBFL);
    uint2* xb3 = (uint2*)((float*)uA + 2 * XBFL);
    float* y   = h1;
    float* v_a = h1 + rnd(4 * BN3);
    float* v_b = v_a + rnd(BN3);

    const int GE  = (E + 255) / 256;
    const int GN  = (N + 255) / 256;               // 196 blocks of 256 nodes
    const int GB8 = GN * 8;
    const int GH4 = GN * 4;
    const int GW  = (N * 64) / 256;
    dim3 blk(256);

    // CSR build (source-bucketed)
    hipMemsetAsync(deg, 0, N * sizeof(float), stream);
    hipMemsetAsync(deg_lo, 0, N * sizeof(int), stream);
    hipMemsetAsync(cur_lo, 0, N * sizeof(int), stream);
    hipMemsetAsync(cur_hi, 0, N * sizeof(int), stream);
    deg2_kernel<<<GE, blk, 0, stream>>>(rowi, coli, deg, deg_lo);
    scan1_kernel<<<GN, blk, 0, stream>>>(deg, part, bsum);
    scan2_kernel<<<1, blk, 0, stream>>>(bsum, boff, GN, rowptr);
    scan3_kernel<<<GN, blk, 0, stream>>>(part, boff, rowptr);
    fill_kernel<<<GE, blk, 0, stream>>>(rowi, coli, rowptr, deg_lo, cur_lo, cur_hi, csr_src);
    dis_kernel<<<GN, blk, 0, stream>>>(deg);
    const float* dis = deg;

    // layer 0
    xprop_kernel<false><<<GB8, blk, 0, stream>>>(x,   rowptr, csr_src, dis, xb1);
    xprop_kernel<true><<<GB8, blk, 0, stream>>>(xb1, rowptr, csr_src, dis, xb2);
    xprop_kernel<true><<<GB8, blk, 0, stream>>>(xb2, rowptr, csr_src, dis, xb3);
    build_h1_kernel<<<GW, blk, 0, stream>>>((const float4*)x, xb1, xb2, xb3, W0, gamma0, beta0, (uint4*)h1);

    const unsigned* H1 = (const unsigned*)h1;
    if (full) {
        hopW_kernel<0><<<GB8, blk, 0, stream>>>(nullptr, rowptr, csr_src, dis, H1, 0, 7, 3,
                                                W1 + 3 * 4096, nullptr, (unsigned*)uA);
        hopW_kernel<1><<<GB8, blk, 0, stream>>>((const unsigned*)uA, rowptr, csr_src, dis, H1, 0, 7, 3,
                                                W1 + 2 * 4096, nullptr, (unsigned*)uB);
        hopW_kernel<1><<<GB8, blk, 0, stream>>>((const unsigned*)uB, rowptr, csr_src, dis, H1, 0, 7, 3,
                                                W1 + 1 * 4096, nullptr, (unsigned*)uA);
        hopW_kernel<2><<<GB8, blk, 0, stream>>>((const unsigned*)uA, rowptr, csr_src, dis, H1, 0, 7, 3,
                                                W1, b1v, (unsigned*)uB);
        bn_project_kernel<<<GW, blk, 0, stream>>>((const uint4*)uB, (const uint4*)(uB + 4 * (size_t)N * 32),
                                                  gamma1, beta1, W2, y);
    } else {
        hopW_kernel<0><<<GB8, blk, 0, stream>>>(nullptr, rowptr, csr_src, dis, H1, 0, 7, 3,
                                                W1 + 3 * 4096, nullptr, (unsigned*)uA);
        hopW_kernel<1><<<GH4, blk, 0, stream>>>((const unsigned*)uA, rowptr, csr_src, dis, H1, 0, 3, 2,
                                                W1 + 2 * 4096, nullptr, (unsigned*)uC);
        hopW_kernel<1><<<GH4, blk, 0, stream>>>((const unsigned*)uC, rowptr, csr_src, dis, H1, 0, 3, 2,
                                                W1 + 1 * 4096, nullptr, (unsigned*)uA);
        hopW_kernel<2><<<GH4, blk, 0, stream>>>((const unsigned*)uA, rowptr, csr_src, dis, H1, 0, 3, 2,
                                                W1, b1v, (unsigned*)uC);
        hopW_kernel<1><<<GH4, blk, 0, stream>>>((const unsigned*)uB, rowptr, csr_src, dis, H1, 4, 3, 2,
                                                W1 + 2 * 4096, nullptr, (unsigned*)uA);
        hopW_kernel<1><<<GH4, blk, 0, stream>>>((const unsigned*)uA, rowptr, csr_src, dis, H1, 4, 3, 2,
                                                W1 + 1 * 4096, nullptr, (unsigned*)uB);
        hopW_kernel<2><<<GH4, blk, 0, stream>>>((const unsigned*)uB, rowptr, csr_src, dis, H1, 4, 3, 2,
                                                W1, b1v, (unsigned*)uA);
        bn_project_kernel<<<GW, blk, 0, stream>>>((const uint4*)uC, (const uint4*)uA,
                                                  gamma1, beta1, W2, y);
    }

    // layer 2 Horner at 3-dim
    qprop_kernel<<<GB8, blk, 0, stream>>>(y + 3 * BN3, rowptr, csr_src, dis, y + 2 * BN3, v_a);
    qprop_kernel<<<GB8, blk, 0, stream>>>(v_a, rowptr, csr_src, dis, y + 1 * BN3, v_b);
    qfinal_kernel<<<GB8, blk, 0, stream>>>(v_b, rowptr, csr_src, dis, y, b2v, vmin, vmax, out);
}